// Round 4
// baseline (1181.925 us; speedup 1.0000x reference)
//
#include <hip/hip_runtime.h>
#include <hip/hip_bf16.h>
#include <math.h>

// MoEHeadAdapter: N=65536, D=256, E=4, H=512, K=2, EMB=512.
// Dense-4-expert compute (scaled by sparse gates) == reference einsum.
// v4 = v3 + fix: Y projection staging goes to Xs (stride 264 >= 256 cols);
// v3 wrote it into Hs (stride 136) -> OOB clobber across rows/waves.
// Weights pre-packed in MFMA B-fragment tile order (1KB per 16n x 32k tile)
// -> every inner-loop weight load is a fully-coalesced 1KB wave read.
// 16-row wave tiles -> H and Y wave-private -> zero barriers in expert loop.
// ws: flag @0 | W1p @4KB (1MB) | W2p @1MB+4KB (1MB) | Wpp @2MB+4KB (256KB).

typedef __attribute__((ext_vector_type(4))) float f32x4;
typedef __attribute__((ext_vector_type(8))) short bf16x8;

#define MFMA16(a, b, c) __builtin_amdgcn_mfma_f32_16x16x32_bf16((a), (b), (c), 0, 0, 0)

__device__ __forceinline__ float bf2f(__hip_bfloat16 v) { return __bfloat162float(v); }

// ---------------- dtype sniff (bf16 vs fp32 input encoding) ----------------
__global__ void k_sniff(const unsigned short* __restrict__ xr, int* __restrict__ flag) {
    int lane = threadIdx.x;
    int cnt = 0;
#pragma unroll
    for (int j = 0; j < 4; ++j) {
        unsigned short v = xr[2 * (lane * 4 + j)];
        int e = (v >> 7) & 0xFF;
        cnt += (e >= 97 && e <= 157) ? 1 : 0;
    }
#pragma unroll
    for (int off = 32; off; off >>= 1) cnt += __shfl_down(cnt, off);
    if (lane == 0) flag[0] = (cnt < 192) ? 1 : 0;  // 1 = fp32 mode
}

// ---------------- weight packer: MFMA B-fragment tile order ----------------
// Tile (16 n x 32 k) = 1KB: lane L holds B[n = n0 + (L&15)][k = k0 + (L>>4)*8 + j],
// stored at tile_base + L*16B + j*2B. One block (64 thr) per tile; 2304 tiles.
__global__ void k_pack(const void* __restrict__ w1,   // [4][256][512]
                       const void* __restrict__ w2,   // [4][512][256]
                       const void* __restrict__ wp,   // [256][512]
                       const int* __restrict__ flag,
                       __hip_bfloat16* __restrict__ w1p,
                       __hip_bfloat16* __restrict__ w2p,
                       __hip_bfloat16* __restrict__ wpp) {
    const int t = blockIdx.x;
    const int L = threadIdx.x;
    const bool f32m = (flag[0] != 0);
    const int ln = L & 15, lq = L >> 4;
    union { short s[8]; bf16x8 v; } u;
    __hip_bfloat16* dst;
    if (t < 1024) {            // W1: B[n=h][k=d], per-e tile layout [hc][ks][nt]
        int e = t >> 8, r = t & 255;
        int hc = r >> 6, ks = (r >> 3) & 7, nt = r & 7;
        int n = hc * 128 + nt * 16 + ln;       // h
        int k0 = ks * 32 + lq * 8;             // d
#pragma unroll
        for (int j = 0; j < 8; ++j) {
            int idx = (e * 256 + k0 + j) * 512 + n;
            __hip_bfloat16 b = f32m ? __float2bfloat16(((const float*)w1)[idx])
                                    : ((const __hip_bfloat16*)w1)[idx];
            u.s[j] = *(const short*)&b;
        }
        dst = w1p + t * 512 + L * 8;
    } else if (t < 2048) {     // W2: B[n=d][k=h], per-e tile layout [hc][kk][ntb]
        int tt = t - 1024;
        int e = tt >> 8, r = tt & 255;
        int hc = r >> 6, kk = (r >> 4) & 3, ntb = r & 15;
        int n = ntb * 16 + ln;                 // d
        int k0 = hc * 128 + kk * 32 + lq * 8;  // h
#pragma unroll
        for (int j = 0; j < 8; ++j) {
            int idx = (e * 512 + k0 + j) * 256 + n;
            __hip_bfloat16 b = f32m ? __float2bfloat16(((const float*)w2)[idx])
                                    : ((const __hip_bfloat16*)w2)[idx];
            u.s[j] = *(const short*)&b;
        }
        dst = w2p + tt * 512 + L * 8;
    } else {                   // Wp: B[n=emb][k=d], tile layout [p][ks][nt]
        int tt = t - 2048;
        int p = tt >> 6, ks = (tt >> 3) & 7, nt = tt & 7;
        int n = p * 128 + nt * 16 + ln;        // emb
        int k0 = ks * 32 + lq * 8;             // d
#pragma unroll
        for (int j = 0; j < 8; ++j) {
            int idx = (k0 + j) * 512 + n;
            __hip_bfloat16 b = f32m ? __float2bfloat16(((const float*)wp)[idx])
                                    : ((const __hip_bfloat16*)wp)[idx];
            u.s[j] = *(const short*)&b;
        }
        dst = wpp + tt * 512 + L * 8;
    }
    *(bf16x8*)dst = u.v;
}

// ---------------- fused: gating + dense expert FFN + out projection ----------------
// grid 512 x 512 threads; block = 128 tokens; wave wr owns tokens 16*wr..+16.
// LDS: Xs [128][264] bf16 (67584) | Hs [128][136] bf16 (34816 @67584)
//      gate_s [128][4] f32 (2048 @102400) | wgs [4][256] f32 (4096 @104448) = 108544
__global__ __launch_bounds__(512) void k_moe(
    const void* __restrict__ xin,             // [65536][256]
    const void* __restrict__ wg,              // [256][4]
    const __hip_bfloat16* __restrict__ w1p,
    const __hip_bfloat16* __restrict__ w2p,
    const __hip_bfloat16* __restrict__ wpp,
    const void* __restrict__ bp,              // [512]
    const int* __restrict__ flag,
    void* __restrict__ outp) {                // [65536][512]
    extern __shared__ char smem[];
    __hip_bfloat16* Xs = (__hip_bfloat16*)smem;             // stride 264
    __hip_bfloat16* Hs = (__hip_bfloat16*)(smem + 67584);   // stride 136
    float* gate_s = (float*)(smem + 102400);
    float* wgs = (float*)(smem + 104448);

    const int tid = threadIdx.x;
    const int m0 = blockIdx.x * 128;
    const bool f32m = (flag[0] != 0);

    // ---- stage X tile as bf16 (padded stride 264 -> 2-way banks, free) ----
    if (!f32m) {
        const uint4* xg = (const uint4*)((const __hip_bfloat16*)xin + (size_t)m0 * 256);
#pragma unroll
        for (int i = 0; i < 8; ++i) {
            int f = tid + 512 * i;
            int r = f >> 5, c = f & 31;
            *(uint4*)&Xs[r * 264 + c * 8] = xg[f];
        }
    } else {
        const float4* xg = (const float4*)((const float*)xin + (size_t)m0 * 256);
#pragma unroll
        for (int i = 0; i < 8; ++i) {
            int f = tid + 512 * i;
            int r = f >> 5, c = f & 31;
            float4 a = xg[2 * f], b = xg[2 * f + 1];
            __hip_bfloat16* d = &Xs[r * 264 + c * 8];
            d[0] = __float2bfloat16(a.x); d[1] = __float2bfloat16(a.y);
            d[2] = __float2bfloat16(a.z); d[3] = __float2bfloat16(a.w);
            d[4] = __float2bfloat16(b.x); d[5] = __float2bfloat16(b.y);
            d[6] = __float2bfloat16(b.z); d[7] = __float2bfloat16(b.w);
        }
    }
    if (tid < 256) {
#pragma unroll
        for (int e = 0; e < 4; ++e)
            wgs[e * 256 + tid] = f32m ? ((const float*)wg)[tid * 4 + e]
                                      : bf2f(((const __hip_bfloat16*)wg)[tid * 4 + e]);
    }
    __syncthreads();

    // ---- gating logits at full input precision (top-k is discrete) ----
    {
        int tok = tid >> 2, e = tid & 3;
        float acc = 0.f;
        const float* wrow = &wgs[e * 256];
        if (f32m) {
            const float4* xrow = (const float4*)((const float*)xin + (size_t)(m0 + tok) * 256);
#pragma unroll 8
            for (int qq = 0; qq < 64; ++qq) {
                float4 xv = xrow[qq];
                acc += xv.x * wrow[qq * 4] + xv.y * wrow[qq * 4 + 1]
                     + xv.z * wrow[qq * 4 + 2] + xv.w * wrow[qq * 4 + 3];
            }
        } else {
#pragma unroll 4
            for (int d8 = 0; d8 < 32; ++d8) {
                bf16x8 xv = *(const bf16x8*)&Xs[tok * 264 + d8 * 8];
#pragma unroll
                for (int j = 0; j < 8; ++j) {
                    union { unsigned u; float f; } c;
                    c.u = ((unsigned)(unsigned short)xv[j]) << 16;
                    acc += c.f * wrow[d8 * 8 + j];
                }
            }
        }
        gate_s[tok * 4 + e] = acc;
    }
    __syncthreads();
    if (tid < 128) {  // top-2 + softmax (ties -> lowest index)
        float l[4];
#pragma unroll
        for (int e = 0; e < 4; ++e) l[e] = gate_s[tid * 4 + e];
        int i0 = 0; float v0 = l[0];
#pragma unroll
        for (int e = 1; e < 4; ++e)
            if (l[e] > v0) { v0 = l[e]; i0 = e; }
        int i1 = -1; float v1 = -1e30f;
#pragma unroll
        for (int e = 0; e < 4; ++e)
            if (e != i0 && l[e] > v1) { v1 = l[e]; i1 = e; }
        float t = expf(v1 - v0);
        float g0 = 1.f / (1.f + t);
        float g1 = t * g0;
#pragma unroll
        for (int e = 0; e < 4; ++e) gate_s[tid * 4 + e] = 0.f;
        gate_s[tid * 4 + i0] = g0;
        gate_s[tid * 4 + i1] = g1;
    }
    __syncthreads();

    const int lane = tid & 63;
    const int wr = tid >> 6;          // 8 waves, 16 tokens each
    const int lm = lane & 15, q = lane >> 4;
    const int rbase = 16 * wr;

    // preload this lane's gates: rows rbase + q*4 + r
    float gl[4][4];
#pragma unroll
    for (int r = 0; r < 4; ++r)
#pragma unroll
        for (int e = 0; e < 4; ++e)
            gl[r][e] = gate_s[(rbase + q * 4 + r) * 4 + e];

    f32x4 Yacc[16];  // wave-private Y: 16 rows x 256 d
#pragma unroll
    for (int b = 0; b < 16; ++b) Yacc[b] = (f32x4){0.f, 0.f, 0.f, 0.f};

    const short* XsS = (const short*)Xs;
    const short* HsS = (const short*)Hs;

#pragma unroll 1
    for (int e = 0; e < 4; ++e) {
        const short* w1e = (const short*)w1p + e * 131072;
        const short* w2e = (const short*)w2p + e * 131072;
#pragma unroll 1
        for (int hc = 0; hc < 4; ++hc) {
            // Phase A: H[16 rows][128 h] = X @ W1 chunk  (wave-private, no barrier)
            f32x4 Hacc[8];
#pragma unroll
            for (int b = 0; b < 8; ++b) Hacc[b] = (f32x4){0.f, 0.f, 0.f, 0.f};
            const short* w1c = w1e + hc * 32768;
#pragma unroll 2
            for (int ks = 0; ks < 8; ++ks) {
                bf16x8 af = *(const bf16x8*)&XsS[(rbase + lm) * 264 + ks * 32 + q * 8];
                const short* bptr = w1c + ks * 4096 + lane * 8;
#pragma unroll
                for (int nt = 0; nt < 8; ++nt)
                    Hacc[nt] = MFMA16(af, *(const bf16x8*)(bptr + nt * 512), Hacc[nt]);
            }
            // gelu(exact) + gate -> wave-private Hs slice (cols 0..127 < 136)
#pragma unroll
            for (int nt = 0; nt < 8; ++nt)
#pragma unroll
                for (int r = 0; r < 4; ++r) {
                    float v = Hacc[nt][r];
                    float g = 0.5f * v * (1.f + erff(v * 0.70710678118654752f)) * gl[r][e];
                    Hs[(rbase + q * 4 + r) * 136 + nt * 16 + lm] = __float2bfloat16(g);
                }
            // Phase B: Y += H @ W2 chunk  (same-wave LDS readback, in-order DS)
            const short* w2c = w2e + hc * 32768;
#pragma unroll 2
            for (int kk = 0; kk < 4; ++kk) {
                bf16x8 af = *(const bf16x8*)&HsS[(rbase + lm) * 136 + kk * 32 + q * 8];
                const short* bptr = w2c + kk * 8192 + lane * 8;
#pragma unroll
                for (int ntb = 0; ntb < 16; ++ntb)
                    Yacc[ntb] = MFMA16(af, *(const bf16x8*)(bptr + ntb * 512), Yacc[ntb]);
            }
        }
    }

    // ---- projection: stage Y (bf16) in wave-private rows of Xs (stride 264 >= 256) ----
#pragma unroll
    for (int ntb = 0; ntb < 16; ++ntb)
#pragma unroll
        for (int r = 0; r < 4; ++r)
            Xs[(rbase + q * 4 + r) * 264 + ntb * 16 + lm] = __float2bfloat16(Yacc[ntb][r]);
    bf16x8 ay[8];
#pragma unroll
    for (int ks = 0; ks < 8; ++ks)
        ay[ks] = *(const bf16x8*)&XsS[(rbase + lm) * 264 + ks * 32 + q * 8];

#pragma unroll 1
    for (int p = 0; p < 4; ++p) {
        f32x4 Oacc[8];
#pragma unroll
        for (int b = 0; b < 8; ++b) Oacc[b] = (f32x4){0.f, 0.f, 0.f, 0.f};
        const short* wpc = (const short*)wpp + p * 32768;
#pragma unroll 2
        for (int ks = 0; ks < 8; ++ks) {
            const short* bptr = wpc + ks * 4096 + lane * 8;
#pragma unroll
            for (int nt = 0; nt < 8; ++nt)
                Oacc[nt] = MFMA16(ay[ks], *(const bf16x8*)(bptr + nt * 512), Oacc[nt]);
        }
#pragma unroll
        for (int nt = 0; nt < 8; ++nt) {
            int col = p * 128 + nt * 16 + lm;
            float bv = f32m ? ((const float*)bp)[col] : bf2f(((const __hip_bfloat16*)bp)[col]);
#pragma unroll
            for (int r = 0; r < 4; ++r) {
                int row = m0 + rbase + q * 4 + r;
                float v = Oacc[nt][r] + bv;
                if (f32m) ((float*)outp)[(size_t)row * 512 + col] = v;
                else ((__hip_bfloat16*)outp)[(size_t)row * 512 + col] = __float2bfloat16(v);
            }
        }
    }
}

extern "C" void kernel_launch(void* const* d_in, const int* in_sizes, int n_in,
                              void* d_out, int out_size, void* d_ws, size_t ws_size,
                              hipStream_t stream) {
    const void* x  = d_in[0];
    const void* wg = d_in[1];
    const void* w1 = d_in[2];
    const void* w2 = d_in[3];
    const void* wp = d_in[4];
    const void* bp = d_in[5];

    char* ws = (char*)d_ws;
    int* flag = (int*)(ws + 0);
    __hip_bfloat16* w1p = (__hip_bfloat16*)(ws + 4096);
    __hip_bfloat16* w2p = (__hip_bfloat16*)(ws + 4096 + (1u << 20));
    __hip_bfloat16* wpp = (__hip_bfloat16*)(ws + 4096 + (2u << 20));

    k_sniff<<<1, 64, 0, stream>>>((const unsigned short*)x, flag);
    k_pack<<<2304, 64, 0, stream>>>(w1, w2, wp, flag, w1p, w2p, wpp);
    k_moe<<<512, 512, 108544, stream>>>(x, wg, w1p, w2p, wpp, bp, flag, d_out);
}